// Round 4
// baseline (1723.769 us; speedup 1.0000x reference)
//
#include <hip/hip_runtime.h>

#define THREADS 256
#define NBLK 256              // blocks for bin passes (private-region radix)
#define BSHIFT 8              // 256 dst-nodes per bucket
#define BSZ (1 << BSHIFT)
#define MAXB 512              // max buckets (N <= 131072)

// ---------- edge_index dtype probe: int64 high-words (values in [0,2^31)) are all 0 ----------
__global__ void detect_kernel(const unsigned int* ei_words, int* flag_int64, long long n_words) {
    __shared__ int nonzero;
    if (threadIdx.x == 0) nonzero = 0;
    __syncthreads();
    long long w = 2LL * threadIdx.x + 1;   // odd word positions = int64 high words
    if (w < n_words) {
        if (ei_words[w] != 0u) atomicOr(&nonzero, 1);
    }
    __syncthreads();
    if (threadIdx.x == 0) *flag_int64 = (nonzero == 0) ? 1 : 0;
}

// ---------- convert to int32 + fused dst-degree histogram ----------
__global__ void convert_kernel(const void* __restrict__ ei, const int* __restrict__ flag_int64,
                               int* __restrict__ out, int* __restrict__ count,
                               long long n, int E) {
    long long i = (long long)blockIdx.x * blockDim.x + threadIdx.x;
    if (i >= n) return;
    int v;
    if (*flag_int64)
        v = (int)((const long long*)ei)[i];
    else
        v = ((const int*)ei)[i];
    out[i] = v;
    if (i >= E) atomicAdd(&count[v], 1);   // second half = dst
}

// ---------- pass 1: per-block bucket histogram ----------
__global__ void bin_count_kernel(const int* __restrict__ dst, int* __restrict__ blockhist,
                                 int E, int NB) {
    __shared__ int h[MAXB];
    int tid = threadIdx.x;
    for (int i = tid; i < NB; i += blockDim.x) h[i] = 0;
    __syncthreads();
    int chunk = (E + gridDim.x - 1) / gridDim.x;
    int s = blockIdx.x * chunk;
    int e = min(E, s + chunk);
    for (int i = s + tid; i < e; i += blockDim.x)
        atomicAdd(&h[dst[i] >> BSHIFT], 1);
    __syncthreads();
    for (int i = tid; i < NB; i += blockDim.x)
        blockhist[i * NBLK + blockIdx.x] = h[i];   // bucket-major for scan
}

// ---------- pass 2: write edges into private (bucket, block) regions; no global atomics ----------
__global__ void bin_write_kernel(const int* __restrict__ src, const int* __restrict__ dst,
                                 const int* __restrict__ offsets, unsigned int* __restrict__ ebuf,
                                 int E, int NB) {
    __shared__ int cur[MAXB];
    int tid = threadIdx.x;
    for (int i = tid; i < NB; i += blockDim.x)
        cur[i] = offsets[i * NBLK + blockIdx.x];
    __syncthreads();
    int chunk = (E + gridDim.x - 1) / gridDim.x;
    int s = blockIdx.x * chunk;
    int e = min(E, s + chunk);
    for (int i = s + tid; i < e; i += blockDim.x) {
        int d = dst[i];
        int b = d >> BSHIFT;
        int pos = atomicAdd(&cur[b], 1);   // LDS cursor -> private region
        ebuf[pos] = ((unsigned int)(d & (BSZ - 1)) << 20) | (unsigned int)src[i];  // src < 2^20
    }
}

// ---------- 3-kernel exclusive scan (1024 elems / block), input cnt -> output ofs ----------
__global__ void scan_blocks_kernel(const int* __restrict__ cnt, int* __restrict__ ofs,
                                   int* __restrict__ partials, int T) {
    __shared__ int sd[THREADS];
    int tid = threadIdx.x;
    int base = blockIdx.x * 1024 + tid * 4;
    int c0 = (base + 0 < T) ? cnt[base + 0] : 0;
    int c1 = (base + 1 < T) ? cnt[base + 1] : 0;
    int c2 = (base + 2 < T) ? cnt[base + 2] : 0;
    int c3 = (base + 3 < T) ? cnt[base + 3] : 0;
    int tsum = c0 + c1 + c2 + c3;
    sd[tid] = tsum;
    __syncthreads();
    for (int off = 1; off < THREADS; off <<= 1) {
        int t = (tid >= off) ? sd[tid - off] : 0;
        __syncthreads();
        sd[tid] += t;
        __syncthreads();
    }
    int excl = sd[tid] - tsum;
    if (base + 0 < T) ofs[base + 0] = excl;
    if (base + 1 < T) ofs[base + 1] = excl + c0;
    if (base + 2 < T) ofs[base + 2] = excl + c0 + c1;
    if (base + 3 < T) ofs[base + 3] = excl + c0 + c1 + c2;
    if (tid == THREADS - 1) partials[blockIdx.x] = sd[tid];
}

__global__ void scan_partials_kernel(int* __restrict__ partials, int* __restrict__ total_out, int B) {
    __shared__ int sd[128];
    int tid = threadIdx.x;  // 128 threads, B <= 128
    int v = (tid < B) ? partials[tid] : 0;
    sd[tid] = v;
    __syncthreads();
    for (int off = 1; off < 128; off <<= 1) {
        int t = (tid >= off) ? sd[tid - off] : 0;
        __syncthreads();
        sd[tid] += t;
        __syncthreads();
    }
    if (tid < B) partials[tid] = sd[tid] - v;     // exclusive
    if (tid == 127) total_out[0] = sd[127];       // grand total -> ofs[T]
}

__global__ void scan_add_kernel(int* __restrict__ ofs, const int* __restrict__ partials, int T) {
    int tid = threadIdx.x;
    int base = blockIdx.x * 1024 + tid * 4;
    int add = partials[blockIdx.x];
    if (base + 0 < T) ofs[base + 0] += add;
    if (base + 1 < T) ofs[base + 1] += add;
    if (base + 2 < T) ofs[base + 2] += add;
    if (base + 3 < T) ofs[base + 3] += add;
}

// ---------- dinv = 1/sqrt(deg), deg = count + 1 (self loop) ----------
__global__ void dinv_kernel(const int* __restrict__ count, float* __restrict__ dinv, int N) {
    int i = blockIdx.x * blockDim.x + threadIdx.x;
    if (i < N) dinv[i] = 1.0f / sqrtf((float)(count[i] + 1));
}

// ---------- dense transform: out = (h @ W^T) * dinv[n] ----------
__global__ void dense_kernel(const float* __restrict__ h, const float* __restrict__ W,
                             const float* __restrict__ dinv, float* __restrict__ out, int N) {
    __shared__ float Wt[1024];   // Wt[k*32 + j] = W[j*32 + k]
    __shared__ float hs[THREADS];
    int tid = threadIdx.x;
    for (int idx = tid; idx < 1024; idx += THREADS) {
        int r = idx >> 5, c = idx & 31;
        Wt[c * 32 + r] = W[idx];
    }
    int gid = blockIdx.x * THREADS + tid;
    int total = N * 32;
    if (gid < total) hs[tid] = h[gid];
    __syncthreads();
    if (gid >= total) return;
    int ln = tid >> 5;   // local node
    int j = tid & 31;    // feature
    const float* hr = hs + ln * 32;
    float s = 0.f;
#pragma unroll
    for (int k = 0; k < 32; ++k) s = fmaf(hr[k], Wt[k * 32 + j], s);
    out[gid] = s * dinv[gid >> 5];
}

// ---------- fused place+aggregate: one block per 256-node bucket ----------
// acc[dl][j] = ht[self] + sum ht[src];  out = relu(dinv*acc + b)
__global__ __launch_bounds__(1024) void agg_bucket_kernel(
        const float* __restrict__ ht, const unsigned int* __restrict__ ebuf,
        const int* __restrict__ offsets, const float* __restrict__ dinv,
        const float* __restrict__ bias, float* __restrict__ out, int N) {
    __shared__ float acc[BSZ * 32];   // 32 KB
    int b = blockIdx.x;
    int lo = b << BSHIFT;
    int nodes = min(BSZ, N - lo);
    int tid = threadIdx.x;
    // init with self-loop term (coalesced)
    for (int i = tid; i < nodes * 32; i += blockDim.x) acc[i] = ht[lo * 32 + i];
    __syncthreads();
    int start = offsets[b * NBLK];
    int end   = offsets[(b + 1) * NBLK];
    int g = tid >> 5, j = tid & 31, ng = blockDim.x >> 5;
    for (int p = start + g; p < end; p += ng) {
        unsigned int v = ebuf[p];            // broadcast within 32-lane group
        int dl = (v >> 20) & (BSZ - 1);
        int s  = (int)(v & 0xFFFFFu);
        atomicAdd(&acc[dl * 32 + j], ht[s * 32 + j]);   // ds_add_f32, conflict-free banks
    }
    __syncthreads();
    for (int i = tid; i < nodes * 32; i += blockDim.x) {
        int n = lo + (i >> 5);
        out[n * 32 + (i & 31)] = fmaxf(fmaf(dinv[n], acc[i], bias[i & 31]), 0.f);
    }
}

extern "C" void kernel_launch(void* const* d_in, const int* in_sizes, int n_in,
                              void* d_out, int out_size, void* d_ws, size_t ws_size,
                              hipStream_t stream) {
    const float* x  = (const float*)d_in[0];
    const void*  ei = d_in[1];
    const float* W1 = (const float*)d_in[2];
    const float* b1 = (const float*)d_in[3];
    const float* W2 = (const float*)d_in[4];
    const float* b2 = (const float*)d_in[5];
    float* out = (float*)d_out;

    int N = in_sizes[0] / 32;
    long long twoE = (long long)in_sizes[1];
    int E = (int)(twoE / 2);
    int NB = (N + BSZ - 1) >> BSHIFT;          // buckets (391 for N=100000)
    int T  = NB * NBLK;                        // blockhist entries (100096)

    char* ws = (char*)d_ws;
    size_t o = 0;
    auto alloc = [&](size_t bytes) { size_t r = o; o += (bytes + 255) & ~(size_t)255; return r; };
    int*   flag      = (int*)(ws + alloc(4));
    int*   e32       = (int*)(ws + alloc((size_t)twoE * 4));   // [src | dst]
    int*   count     = (int*)(ws + alloc((size_t)N * 4));
    int*   blockhist = (int*)(ws + alloc((size_t)T * 4));
    int*   offsets   = (int*)(ws + alloc((size_t)(T + 1) * 4));
    int*   partials  = (int*)(ws + alloc(512));
    float* dinv      = (float*)(ws + alloc((size_t)N * 4));
    unsigned int* ebuf = (unsigned int*)(ws + alloc((size_t)E * 4));
    float* ht        = (float*)(ws + alloc((size_t)N * 32 * 4));
    float* h1        = (float*)(ws + alloc((size_t)N * 32 * 4));
    int* src32 = e32;
    int* dst32 = e32 + E;

    hipMemsetAsync(count, 0, (size_t)N * 4, stream);

    detect_kernel<<<1, 256, 0, stream>>>((const unsigned int*)ei, flag, twoE);
    convert_kernel<<<(int)((twoE + 255) / 256), 256, 0, stream>>>(ei, flag, e32, count, twoE, E);

    bin_count_kernel<<<NBLK, THREADS, 0, stream>>>(dst32, blockhist, E, NB);

    int SB = (T + 1023) / 1024;   // 98 blocks (must be <=128)
    scan_blocks_kernel<<<SB, THREADS, 0, stream>>>(blockhist, offsets, partials, T);
    scan_partials_kernel<<<1, 128, 0, stream>>>(partials, offsets + T, SB);
    scan_add_kernel<<<SB, THREADS, 0, stream>>>(offsets, partials, T);

    dinv_kernel<<<(N + 255) / 256, 256, 0, stream>>>(count, dinv, N);

    bin_write_kernel<<<NBLK, THREADS, 0, stream>>>(src32, dst32, offsets, ebuf, E, NB);

    int GB = (N * 32 + THREADS - 1) / THREADS;
    dense_kernel<<<GB, THREADS, 0, stream>>>(x, W1, dinv, ht, N);
    agg_bucket_kernel<<<NB, 1024, 0, stream>>>(ht, ebuf, offsets, dinv, b1, h1, N);
    dense_kernel<<<GB, THREADS, 0, stream>>>(h1, W2, dinv, ht, N);
    agg_bucket_kernel<<<NB, 1024, 0, stream>>>(ht, ebuf, offsets, dinv, b2, out, N);
}

// Round 5
// 495.651 us; speedup vs baseline: 3.4778x; 3.4778x over previous
//
#include <hip/hip_runtime.h>

#define THREADS 256
#define NBLK 256              // blocks for bin passes (private-region radix)
#define BSHIFT 8              // 256 dst-nodes per bucket
#define BSZ (1 << BSHIFT)
#define MAXB 512              // max buckets (N <= 131072)

// ---------- edge_index dtype probe: int64 high-words (values in [0,2^31)) are all 0 ----------
__global__ void detect_kernel(const unsigned int* ei_words, int* flag_int64, long long n_words) {
    __shared__ int nonzero;
    if (threadIdx.x == 0) nonzero = 0;
    __syncthreads();
    long long w = 2LL * threadIdx.x + 1;   // odd word positions = int64 high words
    if (w < n_words) {
        if (ei_words[w] != 0u) atomicOr(&nonzero, 1);
    }
    __syncthreads();
    if (threadIdx.x == 0) *flag_int64 = (nonzero == 0) ? 1 : 0;
}

// ---------- convert to int32 + fused dst-degree histogram ----------
__global__ void convert_kernel(const void* __restrict__ ei, const int* __restrict__ flag_int64,
                               int* __restrict__ out, int* __restrict__ count,
                               long long n, int E) {
    long long i = (long long)blockIdx.x * blockDim.x + threadIdx.x;
    if (i >= n) return;
    int v;
    if (*flag_int64)
        v = (int)((const long long*)ei)[i];
    else
        v = ((const int*)ei)[i];
    out[i] = v;
    if (i >= E) atomicAdd(&count[v], 1);   // second half = dst
}

// ---------- pass 1: per-block bucket histogram ----------
__global__ void bin_count_kernel(const int* __restrict__ dst, int* __restrict__ blockhist,
                                 int E, int NB) {
    __shared__ int h[MAXB];
    int tid = threadIdx.x;
    for (int i = tid; i < NB; i += blockDim.x) h[i] = 0;
    __syncthreads();
    int chunk = (E + gridDim.x - 1) / gridDim.x;
    int s = blockIdx.x * chunk;
    int e = min(E, s + chunk);
    for (int i = s + tid; i < e; i += blockDim.x)
        atomicAdd(&h[dst[i] >> BSHIFT], 1);
    __syncthreads();
    for (int i = tid; i < NB; i += blockDim.x)
        blockhist[i * NBLK + blockIdx.x] = h[i];   // bucket-major for scan
}

// ---------- pass 2: write edges into private (bucket, block) regions; no global atomics ----------
__global__ void bin_write_kernel(const int* __restrict__ src, const int* __restrict__ dst,
                                 const int* __restrict__ offsets, unsigned int* __restrict__ ebuf,
                                 int E, int NB) {
    __shared__ int cur[MAXB];
    int tid = threadIdx.x;
    for (int i = tid; i < NB; i += blockDim.x)
        cur[i] = offsets[i * NBLK + blockIdx.x];
    __syncthreads();
    int chunk = (E + gridDim.x - 1) / gridDim.x;
    int s = blockIdx.x * chunk;
    int e = min(E, s + chunk);
    for (int i = s + tid; i < e; i += blockDim.x) {
        int d = dst[i];
        int b = d >> BSHIFT;
        int pos = atomicAdd(&cur[b], 1);   // LDS cursor -> private region
        ebuf[pos] = ((unsigned int)(d & (BSZ - 1)) << 20) | (unsigned int)src[i];  // src < 2^20
    }
}

// ---------- 3-kernel exclusive scan (1024 elems / block), input cnt -> output ofs ----------
__global__ void scan_blocks_kernel(const int* __restrict__ cnt, int* __restrict__ ofs,
                                   int* __restrict__ partials, int T) {
    __shared__ int sd[THREADS];
    int tid = threadIdx.x;
    int base = blockIdx.x * 1024 + tid * 4;
    int c0 = (base + 0 < T) ? cnt[base + 0] : 0;
    int c1 = (base + 1 < T) ? cnt[base + 1] : 0;
    int c2 = (base + 2 < T) ? cnt[base + 2] : 0;
    int c3 = (base + 3 < T) ? cnt[base + 3] : 0;
    int tsum = c0 + c1 + c2 + c3;
    sd[tid] = tsum;
    __syncthreads();
    for (int off = 1; off < THREADS; off <<= 1) {
        int t = (tid >= off) ? sd[tid - off] : 0;
        __syncthreads();
        sd[tid] += t;
        __syncthreads();
    }
    int excl = sd[tid] - tsum;
    if (base + 0 < T) ofs[base + 0] = excl;
    if (base + 1 < T) ofs[base + 1] = excl + c0;
    if (base + 2 < T) ofs[base + 2] = excl + c0 + c1;
    if (base + 3 < T) ofs[base + 3] = excl + c0 + c1 + c2;
    if (tid == THREADS - 1) partials[blockIdx.x] = sd[tid];
}

__global__ void scan_partials_kernel(int* __restrict__ partials, int* __restrict__ total_out, int B) {
    __shared__ int sd[128];
    int tid = threadIdx.x;  // 128 threads, B <= 128
    int v = (tid < B) ? partials[tid] : 0;
    sd[tid] = v;
    __syncthreads();
    for (int off = 1; off < 128; off <<= 1) {
        int t = (tid >= off) ? sd[tid - off] : 0;
        __syncthreads();
        sd[tid] += t;
        __syncthreads();
    }
    if (tid < B) partials[tid] = sd[tid] - v;     // exclusive
    if (tid == 127) total_out[0] = sd[127];       // grand total -> ofs[T]
}

__global__ void scan_add_kernel(int* __restrict__ ofs, const int* __restrict__ partials, int T) {
    int tid = threadIdx.x;
    int base = blockIdx.x * 1024 + tid * 4;
    int add = partials[blockIdx.x];
    if (base + 0 < T) ofs[base + 0] += add;
    if (base + 1 < T) ofs[base + 1] += add;
    if (base + 2 < T) ofs[base + 2] += add;
    if (base + 3 < T) ofs[base + 3] += add;
}

// ---------- dinv = 1/sqrt(deg), deg = count + 1 (self loop) ----------
__global__ void dinv_kernel(const int* __restrict__ count, float* __restrict__ dinv, int N) {
    int i = blockIdx.x * blockDim.x + threadIdx.x;
    if (i < N) dinv[i] = 1.0f / sqrtf((float)(count[i] + 1));
}

// ---------- fine place: one block per 256-node bucket; LDS counters; col writes in ~50KB window ----------
__global__ void place_kernel(const unsigned int* __restrict__ ebuf, const int* __restrict__ rowptr,
                             const int* __restrict__ offsets, int* __restrict__ col, int N, int NB) {
    __shared__ int fillL[BSZ];
    __shared__ int baseL[BSZ];
    int b = blockIdx.x;
    int lo = b << BSHIFT;
    int hi = min(lo + BSZ, N);
    int tid = threadIdx.x;
    fillL[tid] = 0;
    baseL[tid] = rowptr[min(lo + tid, N)];
    __syncthreads();
    int start = offsets[b * NBLK];                  // == rowptr[lo]
    int end   = offsets[min(b + 1, NB) * NBLK];     // == rowptr[hi]
    for (int p = start + tid; p < end; p += blockDim.x) {
        unsigned int v = ebuf[p];
        int dl = (v >> 20) & (BSZ - 1);
        int s  = (int)(v & 0xFFFFFu);
        int pos = baseL[dl] + atomicAdd(&fillL[dl], 1);
        col[pos] = s;
    }
}

// ---------- dense transform: out = (h @ W^T) * dinv[n] ----------
__global__ void dense_kernel(const float* __restrict__ h, const float* __restrict__ W,
                             const float* __restrict__ dinv, float* __restrict__ out, int N) {
    __shared__ float Wt[1024];   // Wt[k*32 + j] = W[j*32 + k]
    __shared__ float hs[THREADS];
    int tid = threadIdx.x;
    for (int idx = tid; idx < 1024; idx += THREADS) {
        int r = idx >> 5, c = idx & 31;
        Wt[c * 32 + r] = W[idx];
    }
    int gid = blockIdx.x * THREADS + tid;
    int total = N * 32;
    if (gid < total) hs[tid] = h[gid];
    __syncthreads();
    if (gid >= total) return;
    int ln = tid >> 5;   // local node
    int j = tid & 31;    // feature
    const float* hr = hs + ln * 32;
    float s = 0.f;
#pragma unroll
    for (int k = 0; k < 32; ++k) s = fmaf(hr[k], Wt[k * 32 + j], s);
    out[gid] = s * dinv[gid >> 5];
}

// ---------- aggregate: out = relu(dinv[n] * (self + sum_{nbr} ht[src]) + b[j]) ----------
__global__ void agg_kernel(const float* __restrict__ ht, const int* __restrict__ rowptr,
                           const int* __restrict__ col, const float* __restrict__ dinv,
                           const float* __restrict__ bias, float* __restrict__ out, int N) {
    int gid = blockIdx.x * THREADS + threadIdx.x;
    int n = gid >> 5;
    if (n >= N) return;
    int j = gid & 31;
    float s = ht[gid];                 // self loop (dinv[n] factor applied at end)
    int p = rowptr[n], end = rowptr[n + 1];
    for (; p + 4 <= end; p += 4) {
        int s0 = col[p], s1 = col[p + 1], s2 = col[p + 2], s3 = col[p + 3];
        float v0 = ht[s0 * 32 + j];
        float v1 = ht[s1 * 32 + j];
        float v2 = ht[s2 * 32 + j];
        float v3 = ht[s3 * 32 + j];
        s += (v0 + v1) + (v2 + v3);
    }
    for (; p < end; ++p) s += ht[col[p] * 32 + j];
    out[gid] = fmaxf(fmaf(dinv[n], s, bias[j]), 0.f);
}

extern "C" void kernel_launch(void* const* d_in, const int* in_sizes, int n_in,
                              void* d_out, int out_size, void* d_ws, size_t ws_size,
                              hipStream_t stream) {
    const float* x  = (const float*)d_in[0];
    const void*  ei = d_in[1];
    const float* W1 = (const float*)d_in[2];
    const float* b1 = (const float*)d_in[3];
    const float* W2 = (const float*)d_in[4];
    const float* b2 = (const float*)d_in[5];
    float* out = (float*)d_out;

    int N = in_sizes[0] / 32;
    long long twoE = (long long)in_sizes[1];
    int E = (int)(twoE / 2);
    int NB = (N + BSZ - 1) >> BSHIFT;          // buckets (391 for N=100000)
    int T  = NB * NBLK;                        // blockhist entries (100096)

    char* ws = (char*)d_ws;
    size_t o = 0;
    auto alloc = [&](size_t bytes) { size_t r = o; o += (bytes + 255) & ~(size_t)255; return r; };
    int*   flag      = (int*)(ws + alloc(4));
    int*   e32       = (int*)(ws + alloc((size_t)twoE * 4));   // [src | dst]
    int*   count     = (int*)(ws + alloc((size_t)N * 4));
    int*   blockhist = (int*)(ws + alloc((size_t)T * 4));
    int*   offsets   = (int*)(ws + alloc((size_t)(T + 1) * 4));
    int*   rowptr    = (int*)(ws + alloc((size_t)(N + 1) * 4));
    int*   partials  = (int*)(ws + alloc(512));
    float* dinv      = (float*)(ws + alloc((size_t)N * 4));
    unsigned int* ebuf = (unsigned int*)(ws + alloc((size_t)E * 4));
    int*   col       = (int*)(ws + alloc((size_t)E * 4));
    float* ht        = (float*)(ws + alloc((size_t)N * 32 * 4));
    float* h1        = (float*)(ws + alloc((size_t)N * 32 * 4));
    int* src32 = e32;
    int* dst32 = e32 + E;

    hipMemsetAsync(count, 0, (size_t)N * 4, stream);

    detect_kernel<<<1, 256, 0, stream>>>((const unsigned int*)ei, flag, twoE);
    convert_kernel<<<(int)((twoE + 255) / 256), 256, 0, stream>>>(ei, flag, e32, count, twoE, E);

    bin_count_kernel<<<NBLK, THREADS, 0, stream>>>(dst32, blockhist, E, NB);

    // scan #1: node-level count -> rowptr  (T = N)
    int SB1 = (N + 1023) / 1024;   // 98 (<=128)
    scan_blocks_kernel<<<SB1, THREADS, 0, stream>>>(count, rowptr, partials, N);
    scan_partials_kernel<<<1, 128, 0, stream>>>(partials, rowptr + N, SB1);
    scan_add_kernel<<<SB1, THREADS, 0, stream>>>(rowptr, partials, N);

    // scan #2: (bucket, block) hist -> ebuf offsets  (T = NB*NBLK)
    int SB2 = (T + 1023) / 1024;   // 98 (<=128)
    scan_blocks_kernel<<<SB2, THREADS, 0, stream>>>(blockhist, offsets, partials, T);
    scan_partials_kernel<<<1, 128, 0, stream>>>(partials, offsets + T, SB2);
    scan_add_kernel<<<SB2, THREADS, 0, stream>>>(offsets, partials, T);

    dinv_kernel<<<(N + 255) / 256, 256, 0, stream>>>(count, dinv, N);

    bin_write_kernel<<<NBLK, THREADS, 0, stream>>>(src32, dst32, offsets, ebuf, E, NB);
    place_kernel<<<NB, BSZ, 0, stream>>>(ebuf, rowptr, offsets, col, N, NB);

    int GB = (N * 32 + THREADS - 1) / THREADS;
    dense_kernel<<<GB, THREADS, 0, stream>>>(x, W1, dinv, ht, N);
    agg_kernel<<<GB, THREADS, 0, stream>>>(ht, rowptr, col, dinv, b1, h1, N);
    dense_kernel<<<GB, THREADS, 0, stream>>>(h1, W2, dinv, ht, N);
    agg_kernel<<<GB, THREADS, 0, stream>>>(ht, rowptr, col, dinv, b2, out, N);
}

// Round 7
// 356.594 us; speedup vs baseline: 4.8340x; 1.3900x over previous
//
#include <hip/hip_runtime.h>

#define THREADS 256
#define NBLK 256              // blocks for bin passes (private-region radix)
#define BSHIFT 8              // 256 dst-nodes per bucket
#define BSZ (1 << BSHIFT)
#define MAXB 512              // max buckets (N <= 131072)

// ---------- edge_index dtype probe: int64 high-words (values in [0,2^31)) are all 0 ----------
__global__ void detect_kernel(const unsigned int* ei_words, int* flag_int64, long long n_words) {
    __shared__ int nonzero;
    if (threadIdx.x == 0) nonzero = 0;
    __syncthreads();
    long long w = 2LL * threadIdx.x + 1;   // odd word positions = int64 high words
    if (w < n_words) {
        if (ei_words[w] != 0u) atomicOr(&nonzero, 1);
    }
    __syncthreads();
    if (threadIdx.x == 0) *flag_int64 = (nonzero == 0) ? 1 : 0;
}

// ---------- pass 1: per-block bucket histogram over dst (reads raw edge_index) ----------
__global__ void bin_count_kernel(const void* __restrict__ ei, const int* __restrict__ flag_int64,
                                 int* __restrict__ blockhist, int E, int NB) {
    __shared__ int h[MAXB];
    int tid = threadIdx.x;
    for (int i = tid; i < NB; i += blockDim.x) h[i] = 0;
    __syncthreads();
    int chunk = (E + gridDim.x - 1) / gridDim.x;
    int s = blockIdx.x * chunk;
    int e = min(E, s + chunk);
    if (*flag_int64) {
        const long long* p = (const long long*)ei;
        for (int i = s + tid; i < e; i += blockDim.x)
            atomicAdd(&h[(int)p[E + i] >> BSHIFT], 1);
    } else {
        const int* p = (const int*)ei;
        for (int i = s + tid; i < e; i += blockDim.x)
            atomicAdd(&h[p[E + i] >> BSHIFT], 1);
    }
    __syncthreads();
    for (int i = tid; i < NB; i += blockDim.x)
        blockhist[i * NBLK + blockIdx.x] = h[i];   // bucket-major for scan
}

// ---------- pass 2: write edges into private (bucket, block) regions; no global atomics ----------
__global__ void bin_write_kernel(const void* __restrict__ ei, const int* __restrict__ flag_int64,
                                 const int* __restrict__ offsets, unsigned int* __restrict__ ebuf,
                                 int E, int NB) {
    __shared__ int cur[MAXB];
    int tid = threadIdx.x;
    for (int i = tid; i < NB; i += blockDim.x)
        cur[i] = offsets[i * NBLK + blockIdx.x];
    __syncthreads();
    int chunk = (E + gridDim.x - 1) / gridDim.x;
    int s = blockIdx.x * chunk;
    int e = min(E, s + chunk);
    if (*flag_int64) {
        const long long* p = (const long long*)ei;
        for (int i = s + tid; i < e; i += blockDim.x) {
            int d = (int)p[E + i];
            int sr = (int)p[i];
            int pos = atomicAdd(&cur[d >> BSHIFT], 1);   // LDS cursor -> private region
            ebuf[pos] = ((unsigned int)(d & (BSZ - 1)) << 20) | (unsigned int)sr;  // src < 2^20
        }
    } else {
        const int* p = (const int*)ei;
        for (int i = s + tid; i < e; i += blockDim.x) {
            int d = p[E + i];
            int sr = p[i];
            int pos = atomicAdd(&cur[d >> BSHIFT], 1);
            ebuf[pos] = ((unsigned int)(d & (BSZ - 1)) << 20) | (unsigned int)sr;
        }
    }
}

// ---------- 3-kernel exclusive scan (1024 elems / block), input cnt -> output ofs ----------
__global__ void scan_blocks_kernel(const int* __restrict__ cnt, int* __restrict__ ofs,
                                   int* __restrict__ partials, int T) {
    __shared__ int sd[THREADS];
    int tid = threadIdx.x;
    int base = blockIdx.x * 1024 + tid * 4;
    int c0 = (base + 0 < T) ? cnt[base + 0] : 0;
    int c1 = (base + 1 < T) ? cnt[base + 1] : 0;
    int c2 = (base + 2 < T) ? cnt[base + 2] : 0;
    int c3 = (base + 3 < T) ? cnt[base + 3] : 0;
    int tsum = c0 + c1 + c2 + c3;
    sd[tid] = tsum;
    __syncthreads();
    for (int off = 1; off < THREADS; off <<= 1) {
        int t = (tid >= off) ? sd[tid - off] : 0;
        __syncthreads();
        sd[tid] += t;
        __syncthreads();
    }
    int excl = sd[tid] - tsum;
    if (base + 0 < T) ofs[base + 0] = excl;
    if (base + 1 < T) ofs[base + 1] = excl + c0;
    if (base + 2 < T) ofs[base + 2] = excl + c0 + c1;
    if (base + 3 < T) ofs[base + 3] = excl + c0 + c1 + c2;
    if (tid == THREADS - 1) partials[blockIdx.x] = sd[tid];
}

__global__ void scan_partials_kernel(int* __restrict__ partials, int* __restrict__ total_out, int B) {
    __shared__ int sd[128];
    int tid = threadIdx.x;  // 128 threads, B <= 128
    int v = (tid < B) ? partials[tid] : 0;
    sd[tid] = v;
    __syncthreads();
    for (int off = 1; off < 128; off <<= 1) {
        int t = (tid >= off) ? sd[tid - off] : 0;
        __syncthreads();
        sd[tid] += t;
        __syncthreads();
    }
    if (tid < B) partials[tid] = sd[tid] - v;     // exclusive
    if (tid == 127) total_out[0] = sd[127];       // grand total -> ofs[T]
}

__global__ void scan_add_kernel(int* __restrict__ ofs, const int* __restrict__ partials, int T) {
    int tid = threadIdx.x;
    int base = blockIdx.x * 1024 + tid * 4;
    int add = partials[blockIdx.x];
    if (base + 0 < T) ofs[base + 0] += add;
    if (base + 1 < T) ofs[base + 1] += add;
    if (base + 2 < T) ofs[base + 2] += add;
    if (base + 3 < T) ofs[base + 3] += add;
}

// ---------- fused per-bucket: degree count + rowptr + dinv + col placement ----------
// one 256-thread block per 256-node bucket; everything via LDS, no global atomics
__global__ __launch_bounds__(BSZ) void place_kernel(
        const unsigned int* __restrict__ ebuf, const int* __restrict__ offsets,
        int* __restrict__ rowptr, float* __restrict__ dinv, int* __restrict__ col,
        int N, int NB) {
    __shared__ int cnt[BSZ];
    __shared__ int scanbuf[BSZ];
    __shared__ int baseL[BSZ];
    __shared__ int fillL[BSZ];
    int b = blockIdx.x;
    int lo = b << BSHIFT;
    int tid = threadIdx.x;
    cnt[tid] = 0;
    __syncthreads();
    int start = offsets[b * NBLK];
    int end   = offsets[(b + 1) * NBLK];   // b = NB-1 reads offsets[T] = E
    // pass A: per-node degree count (ebuf region ~32KB, L2-resident)
    for (int p = start + tid; p < end; p += BSZ)
        atomicAdd(&cnt[(ebuf[p] >> 20) & (BSZ - 1)], 1);
    __syncthreads();
    // exclusive scan of cnt
    int c = cnt[tid];
    scanbuf[tid] = c;
    __syncthreads();
    for (int off = 1; off < BSZ; off <<= 1) {
        int t = (tid >= off) ? scanbuf[tid - off] : 0;
        __syncthreads();
        scanbuf[tid] += t;
        __syncthreads();
    }
    int excl = scanbuf[tid] - c;
    int node = lo + tid;
    if (node < N) {
        rowptr[node] = start + excl;
        dinv[node] = 1.0f / sqrtf((float)(c + 1));   // +1 self loop
        if (node == N - 1) rowptr[N] = start + excl + c;   // == E
    }
    baseL[tid] = start + excl;
    fillL[tid] = 0;
    __syncthreads();
    // pass B: place (col writes confined to this bucket's ~50KB window)
    for (int p = start + tid; p < end; p += BSZ) {
        unsigned int v = ebuf[p];
        int dl = (v >> 20) & (BSZ - 1);
        int pos = baseL[dl] + atomicAdd(&fillL[dl], 1);
        col[pos] = (int)(v & 0xFFFFFu);
    }
}

// ---------- dense transform: out = (h @ W^T) * dinv[n] ----------
__global__ void dense_kernel(const float* __restrict__ h, const float* __restrict__ W,
                             const float* __restrict__ dinv, float* __restrict__ out, int N) {
    __shared__ float Wt[1024];   // Wt[k*32 + j] = W[j*32 + k]
    __shared__ float hs[THREADS];
    int tid = threadIdx.x;
    for (int idx = tid; idx < 1024; idx += THREADS) {
        int r = idx >> 5, c = idx & 31;
        Wt[c * 32 + r] = W[idx];
    }
    int gid = blockIdx.x * THREADS + tid;
    int total = N * 32;
    if (gid < total) hs[tid] = h[gid];
    __syncthreads();
    if (gid >= total) return;
    int ln = tid >> 5;   // local node
    int j = tid & 31;    // feature
    const float* hr = hs + ln * 32;
    float s = 0.f;
#pragma unroll
    for (int k = 0; k < 32; ++k) s = fmaf(hr[k], Wt[k * 32 + j], s);
    out[gid] = s * dinv[gid >> 5];
}

// ---------- aggregate: out = relu(dinv[n] * (self + sum_{nbr} ht[src]) + b[j]) ----------
__global__ void agg_kernel(const float* __restrict__ ht, const int* __restrict__ rowptr,
                           const int* __restrict__ col, const float* __restrict__ dinv,
                           const float* __restrict__ bias, float* __restrict__ out, int N) {
    int gid = blockIdx.x * THREADS + threadIdx.x;
    int n = gid >> 5;
    if (n >= N) return;
    int j = gid & 31;
    float s = ht[gid];                 // self loop (dinv[n] factor applied at end)
    int p = rowptr[n], end = rowptr[n + 1];
    for (; p + 4 <= end; p += 4) {
        int s0 = col[p], s1 = col[p + 1], s2 = col[p + 2], s3 = col[p + 3];
        float v0 = ht[s0 * 32 + j];
        float v1 = ht[s1 * 32 + j];
        float v2 = ht[s2 * 32 + j];
        float v3 = ht[s3 * 32 + j];
        s += (v0 + v1) + (v2 + v3);
    }
    for (; p < end; ++p) s += ht[col[p] * 32 + j];
    out[gid] = fmaxf(fmaf(dinv[n], s, bias[j]), 0.f);
}

extern "C" void kernel_launch(void* const* d_in, const int* in_sizes, int n_in,
                              void* d_out, int out_size, void* d_ws, size_t ws_size,
                              hipStream_t stream) {
    const float* x  = (const float*)d_in[0];
    const void*  ei = d_in[1];
    const float* W1 = (const float*)d_in[2];
    const float* b1 = (const float*)d_in[3];
    const float* W2 = (const float*)d_in[4];
    const float* b2 = (const float*)d_in[5];
    float* out = (float*)d_out;

    int N = in_sizes[0] / 32;
    long long twoE = (long long)in_sizes[1];
    int E = (int)(twoE / 2);
    int NB = (N + BSZ - 1) >> BSHIFT;          // buckets (391 for N=100000)
    int T  = NB * NBLK;                        // blockhist entries (100096)

    char* ws = (char*)d_ws;
    size_t o = 0;
    auto alloc = [&](size_t bytes) { size_t r = o; o += (bytes + 255) & ~(size_t)255; return r; };
    int*   flag      = (int*)(ws + alloc(4));
    int*   blockhist = (int*)(ws + alloc((size_t)T * 4));
    int*   offsets   = (int*)(ws + alloc((size_t)(T + 1) * 4));
    int*   rowptr    = (int*)(ws + alloc((size_t)(N + 1) * 4));
    int*   partials  = (int*)(ws + alloc(512));
    float* dinv      = (float*)(ws + alloc((size_t)N * 4));
    unsigned int* ebuf = (unsigned int*)(ws + alloc((size_t)E * 4));
    int*   col       = (int*)(ws + alloc((size_t)E * 4));
    float* ht        = (float*)(ws + alloc((size_t)N * 32 * 4));
    float* h1        = (float*)(ws + alloc((size_t)N * 32 * 4));

    detect_kernel<<<1, 256, 0, stream>>>((const unsigned int*)ei, flag, twoE);

    bin_count_kernel<<<NBLK, THREADS, 0, stream>>>(ei, flag, blockhist, E, NB);

    // scan: (bucket, block) hist -> ebuf offsets  (T = NB*NBLK)
    int SB = (T + 1023) / 1024;   // 98 (<=128)
    scan_blocks_kernel<<<SB, THREADS, 0, stream>>>(blockhist, offsets, partials, T);
    scan_partials_kernel<<<1, 128, 0, stream>>>(partials, offsets + T, SB);
    scan_add_kernel<<<SB, THREADS, 0, stream>>>(offsets, partials, T);

    bin_write_kernel<<<NBLK, THREADS, 0, stream>>>(ei, flag, offsets, ebuf, E, NB);
    place_kernel<<<NB, BSZ, 0, stream>>>(ebuf, offsets, rowptr, dinv, col, N, NB);

    int GB = (N * 32 + THREADS - 1) / THREADS;
    dense_kernel<<<GB, THREADS, 0, stream>>>(x, W1, dinv, ht, N);
    agg_kernel<<<GB, THREADS, 0, stream>>>(ht, rowptr, col, dinv, b1, h1, N);
    dense_kernel<<<GB, THREADS, 0, stream>>>(h1, W2, dinv, ht, N);
    agg_kernel<<<GB, THREADS, 0, stream>>>(ht, rowptr, col, dinv, b2, out, N);
}

// Round 8
// 313.256 us; speedup vs baseline: 5.5027x; 1.1383x over previous
//
#include <hip/hip_runtime.h>

#define THREADS 256
#define BIGT 1024             // wide blocks for latency-bound passes
#define NBLK 256              // blocks for bin passes (private-region radix)
#define BSHIFT 8              // 256 dst-nodes per bucket
#define BSZ (1 << BSHIFT)
#define MAXB 512              // max buckets (N <= 131072)

// ---------- edge_index dtype probe: int64 high-words (values in [0,2^31)) are all 0 ----------
__global__ void detect_kernel(const unsigned int* ei_words, int* flag_int64, long long n_words) {
    __shared__ int nonzero;
    if (threadIdx.x == 0) nonzero = 0;
    __syncthreads();
    long long w = 2LL * threadIdx.x + 1;   // odd word positions = int64 high words
    if (w < n_words) {
        if (ei_words[w] != 0u) atomicOr(&nonzero, 1);
    }
    __syncthreads();
    if (threadIdx.x == 0) *flag_int64 = (nonzero == 0) ? 1 : 0;
}

// ---------- pass 1: per-block bucket histogram over dst (reads raw edge_index) ----------
__global__ __launch_bounds__(BIGT) void bin_count_kernel(
        const void* __restrict__ ei, const int* __restrict__ flag_int64,
        int* __restrict__ blockhist, int E, int NB) {
    __shared__ int h[MAXB];
    int tid = threadIdx.x;
    for (int i = tid; i < NB; i += blockDim.x) h[i] = 0;
    __syncthreads();
    int chunk = (E + gridDim.x - 1) / gridDim.x;
    int s = blockIdx.x * chunk;
    int e = min(E, s + chunk);
    if (*flag_int64) {
        const long long* p = (const long long*)ei;
        for (int i = s + tid; i < e; i += blockDim.x)
            atomicAdd(&h[(int)p[E + i] >> BSHIFT], 1);
    } else {
        const int* p = (const int*)ei;
        for (int i = s + tid; i < e; i += blockDim.x)
            atomicAdd(&h[p[E + i] >> BSHIFT], 1);
    }
    __syncthreads();
    for (int i = tid; i < NB; i += blockDim.x)
        blockhist[i * NBLK + blockIdx.x] = h[i];   // bucket-major for scan
}

// ---------- pass 2: write edges into private (bucket, block) regions; no global atomics ----------
__global__ __launch_bounds__(BIGT) void bin_write_kernel(
        const void* __restrict__ ei, const int* __restrict__ flag_int64,
        const int* __restrict__ offsets, unsigned int* __restrict__ ebuf,
        int E, int NB) {
    __shared__ int cur[MAXB];
    int tid = threadIdx.x;
    for (int i = tid; i < NB; i += blockDim.x)
        cur[i] = offsets[i * NBLK + blockIdx.x];
    __syncthreads();
    int chunk = (E + gridDim.x - 1) / gridDim.x;
    int s = blockIdx.x * chunk;
    int e = min(E, s + chunk);
    if (*flag_int64) {
        const long long* p = (const long long*)ei;
        for (int i = s + tid; i < e; i += blockDim.x) {
            int d = (int)p[E + i];
            int sr = (int)p[i];
            int pos = atomicAdd(&cur[d >> BSHIFT], 1);   // LDS cursor -> private region
            ebuf[pos] = ((unsigned int)(d & (BSZ - 1)) << 20) | (unsigned int)sr;  // src < 2^20
        }
    } else {
        const int* p = (const int*)ei;
        for (int i = s + tid; i < e; i += blockDim.x) {
            int d = p[E + i];
            int sr = p[i];
            int pos = atomicAdd(&cur[d >> BSHIFT], 1);
            ebuf[pos] = ((unsigned int)(d & (BSZ - 1)) << 20) | (unsigned int)sr;
        }
    }
}

// ---------- 3-kernel exclusive scan (1024 elems / block), input cnt -> output ofs ----------
__global__ void scan_blocks_kernel(const int* __restrict__ cnt, int* __restrict__ ofs,
                                   int* __restrict__ partials, int T) {
    __shared__ int sd[THREADS];
    int tid = threadIdx.x;
    int base = blockIdx.x * 1024 + tid * 4;
    int c0 = (base + 0 < T) ? cnt[base + 0] : 0;
    int c1 = (base + 1 < T) ? cnt[base + 1] : 0;
    int c2 = (base + 2 < T) ? cnt[base + 2] : 0;
    int c3 = (base + 3 < T) ? cnt[base + 3] : 0;
    int tsum = c0 + c1 + c2 + c3;
    sd[tid] = tsum;
    __syncthreads();
    for (int off = 1; off < THREADS; off <<= 1) {
        int t = (tid >= off) ? sd[tid - off] : 0;
        __syncthreads();
        sd[tid] += t;
        __syncthreads();
    }
    int excl = sd[tid] - tsum;
    if (base + 0 < T) ofs[base + 0] = excl;
    if (base + 1 < T) ofs[base + 1] = excl + c0;
    if (base + 2 < T) ofs[base + 2] = excl + c0 + c1;
    if (base + 3 < T) ofs[base + 3] = excl + c0 + c1 + c2;
    if (tid == THREADS - 1) partials[blockIdx.x] = sd[tid];
}

__global__ void scan_partials_kernel(int* __restrict__ partials, int* __restrict__ total_out, int B) {
    __shared__ int sd[128];
    int tid = threadIdx.x;  // 128 threads, B <= 128
    int v = (tid < B) ? partials[tid] : 0;
    sd[tid] = v;
    __syncthreads();
    for (int off = 1; off < 128; off <<= 1) {
        int t = (tid >= off) ? sd[tid - off] : 0;
        __syncthreads();
        sd[tid] += t;
        __syncthreads();
    }
    if (tid < B) partials[tid] = sd[tid] - v;     // exclusive
    if (tid == 127) total_out[0] = sd[127];       // grand total -> ofs[T]
}

__global__ void scan_add_kernel(int* __restrict__ ofs, const int* __restrict__ partials, int T) {
    int tid = threadIdx.x;
    int base = blockIdx.x * 1024 + tid * 4;
    int add = partials[blockIdx.x];
    if (base + 0 < T) ofs[base + 0] += add;
    if (base + 1 < T) ofs[base + 1] += add;
    if (base + 2 < T) ofs[base + 2] += add;
    if (base + 3 < T) ofs[base + 3] += add;
}

// ---------- fused per-bucket: degree count + rowptr + dinv + col placement ----------
// one 1024-thread block per 256-node bucket; everything via LDS, no global atomics
__global__ __launch_bounds__(BIGT) void place_kernel(
        const unsigned int* __restrict__ ebuf, const int* __restrict__ offsets,
        int* __restrict__ rowptr, float* __restrict__ dinv, int* __restrict__ col,
        int N, int NB) {
    __shared__ int cnt[BSZ];
    __shared__ int scanbuf[BSZ];
    __shared__ int baseL[BSZ];
    __shared__ int fillL[BSZ];
    int b = blockIdx.x;
    int lo = b << BSHIFT;
    int tid = threadIdx.x;
    if (tid < BSZ) cnt[tid] = 0;
    __syncthreads();
    int start = offsets[b * NBLK];
    int end   = offsets[(b + 1) * NBLK];   // b = NB-1 reads offsets[T] = E
    // pass A: per-node degree count (ebuf region ~32KB, L2-resident)
    for (int p = start + tid; p < end; p += BIGT)
        atomicAdd(&cnt[(ebuf[p] >> 20) & (BSZ - 1)], 1);
    __syncthreads();
    // exclusive scan of cnt (all threads run loop; only tid<BSZ touch LDS)
    int c = (tid < BSZ) ? cnt[tid] : 0;
    if (tid < BSZ) scanbuf[tid] = c;
    __syncthreads();
    for (int off = 1; off < BSZ; off <<= 1) {
        int t = (tid < BSZ && tid >= off) ? scanbuf[tid - off] : 0;
        __syncthreads();
        if (tid < BSZ) scanbuf[tid] += t;
        __syncthreads();
    }
    if (tid < BSZ) {
        int excl = scanbuf[tid] - c;
        int node = lo + tid;
        if (node < N) {
            rowptr[node] = start + excl;
            dinv[node] = 1.0f / sqrtf((float)(c + 1));   // +1 self loop
            if (node == N - 1) rowptr[N] = start + excl + c;   // == E
        }
        baseL[tid] = start + excl;
        fillL[tid] = 0;
    }
    __syncthreads();
    // pass B: place (col writes confined to this bucket's ~50KB window; ebuf re-read is L2-hit)
    for (int p = start + tid; p < end; p += BIGT) {
        unsigned int v = ebuf[p];
        int dl = (v >> 20) & (BSZ - 1);
        int pos = baseL[dl] + atomicAdd(&fillL[dl], 1);
        col[pos] = (int)(v & 0xFFFFFu);
    }
}

// ---------- dense transform: out = (h @ W^T) * dinv[n] ----------
__global__ void dense_kernel(const float* __restrict__ h, const float* __restrict__ W,
                             const float* __restrict__ dinv, float* __restrict__ out, int N) {
    __shared__ float Wt[1024];   // Wt[k*32 + j] = W[j*32 + k]
    __shared__ float hs[THREADS];
    int tid = threadIdx.x;
    for (int idx = tid; idx < 1024; idx += THREADS) {
        int r = idx >> 5, c = idx & 31;
        Wt[c * 32 + r] = W[idx];
    }
    int gid = blockIdx.x * THREADS + tid;
    int total = N * 32;
    if (gid < total) hs[tid] = h[gid];
    __syncthreads();
    if (gid >= total) return;
    int ln = tid >> 5;   // local node
    int j = tid & 31;    // feature
    const float* hr = hs + ln * 32;
    float s = 0.f;
#pragma unroll
    for (int k = 0; k < 32; ++k) s = fmaf(hr[k], Wt[k * 32 + j], s);
    out[gid] = s * dinv[gid >> 5];
}

// ---------- aggregate: out = relu(dinv[n] * (self + sum_{nbr} ht[src]) + b[j]) ----------
__global__ void agg_kernel(const float* __restrict__ ht, const int* __restrict__ rowptr,
                           const int* __restrict__ col, const float* __restrict__ dinv,
                           const float* __restrict__ bias, float* __restrict__ out, int N) {
    int gid = blockIdx.x * THREADS + threadIdx.x;
    int n = gid >> 5;
    if (n >= N) return;
    int j = gid & 31;
    float s = ht[gid];                 // self loop (dinv[n] factor applied at end)
    int p = rowptr[n], end = rowptr[n + 1];
    // unroll-8: 8 independent gathers in flight per thread
    for (; p + 8 <= end; p += 8) {
        int c0 = col[p], c1 = col[p + 1], c2 = col[p + 2], c3 = col[p + 3];
        int c4 = col[p + 4], c5 = col[p + 5], c6 = col[p + 6], c7 = col[p + 7];
        float v0 = ht[c0 * 32 + j];
        float v1 = ht[c1 * 32 + j];
        float v2 = ht[c2 * 32 + j];
        float v3 = ht[c3 * 32 + j];
        float v4 = ht[c4 * 32 + j];
        float v5 = ht[c5 * 32 + j];
        float v6 = ht[c6 * 32 + j];
        float v7 = ht[c7 * 32 + j];
        s += ((v0 + v1) + (v2 + v3)) + ((v4 + v5) + (v6 + v7));
    }
    for (; p + 4 <= end; p += 4) {
        int c0 = col[p], c1 = col[p + 1], c2 = col[p + 2], c3 = col[p + 3];
        float v0 = ht[c0 * 32 + j];
        float v1 = ht[c1 * 32 + j];
        float v2 = ht[c2 * 32 + j];
        float v3 = ht[c3 * 32 + j];
        s += (v0 + v1) + (v2 + v3);
    }
    for (; p < end; ++p) s += ht[col[p] * 32 + j];
    out[gid] = fmaxf(fmaf(dinv[n], s, bias[j]), 0.f);
}

extern "C" void kernel_launch(void* const* d_in, const int* in_sizes, int n_in,
                              void* d_out, int out_size, void* d_ws, size_t ws_size,
                              hipStream_t stream) {
    const float* x  = (const float*)d_in[0];
    const void*  ei = d_in[1];
    const float* W1 = (const float*)d_in[2];
    const float* b1 = (const float*)d_in[3];
    const float* W2 = (const float*)d_in[4];
    const float* b2 = (const float*)d_in[5];
    float* out = (float*)d_out;

    int N = in_sizes[0] / 32;
    long long twoE = (long long)in_sizes[1];
    int E = (int)(twoE / 2);
    int NB = (N + BSZ - 1) >> BSHIFT;          // buckets (391 for N=100000)
    int T  = NB * NBLK;                        // blockhist entries (100096)

    char* ws = (char*)d_ws;
    size_t o = 0;
    auto alloc = [&](size_t bytes) { size_t r = o; o += (bytes + 255) & ~(size_t)255; return r; };
    int*   flag      = (int*)(ws + alloc(4));
    int*   blockhist = (int*)(ws + alloc((size_t)T * 4));
    int*   offsets   = (int*)(ws + alloc((size_t)(T + 1) * 4));
    int*   rowptr    = (int*)(ws + alloc((size_t)(N + 1) * 4));
    int*   partials  = (int*)(ws + alloc(512));
    float* dinv      = (float*)(ws + alloc((size_t)N * 4));
    unsigned int* ebuf = (unsigned int*)(ws + alloc((size_t)E * 4));
    int*   col       = (int*)(ws + alloc((size_t)E * 4));
    float* ht        = (float*)(ws + alloc((size_t)N * 32 * 4));
    float* h1        = (float*)(ws + alloc((size_t)N * 32 * 4));

    detect_kernel<<<1, 256, 0, stream>>>((const unsigned int*)ei, flag, twoE);

    bin_count_kernel<<<NBLK, BIGT, 0, stream>>>(ei, flag, blockhist, E, NB);

    // scan: (bucket, block) hist -> ebuf offsets  (T = NB*NBLK)
    int SB = (T + 1023) / 1024;   // 98 (<=128)
    scan_blocks_kernel<<<SB, THREADS, 0, stream>>>(blockhist, offsets, partials, T);
    scan_partials_kernel<<<1, 128, 0, stream>>>(partials, offsets + T, SB);
    scan_add_kernel<<<SB, THREADS, 0, stream>>>(offsets, partials, T);

    bin_write_kernel<<<NBLK, BIGT, 0, stream>>>(ei, flag, offsets, ebuf, E, NB);
    place_kernel<<<NB, BIGT, 0, stream>>>(ebuf, offsets, rowptr, dinv, col, N, NB);

    int GB = (N * 32 + THREADS - 1) / THREADS;
    dense_kernel<<<GB, THREADS, 0, stream>>>(x, W1, dinv, ht, N);
    agg_kernel<<<GB, THREADS, 0, stream>>>(ht, rowptr, col, dinv, b1, h1, N);
    dense_kernel<<<GB, THREADS, 0, stream>>>(h1, W2, dinv, ht, N);
    agg_kernel<<<GB, THREADS, 0, stream>>>(ht, rowptr, col, dinv, b2, out, N);
}

// Round 9
// 272.840 us; speedup vs baseline: 6.3179x; 1.1481x over previous
//
#include <hip/hip_runtime.h>

#define THREADS 256
#define BIGT 1024             // wide blocks for latency-bound passes
#define NBLK 256              // blocks for bin passes (private-region radix)
#define BSHIFT 8              // 256 dst-nodes per bucket
#define BSZ (1 << BSHIFT)
#define MAXB 512              // max buckets (N <= 131072)

// ---------- edge_index dtype probe: int64 high-words (values in [0,2^31)) are all 0 ----------
__global__ void detect_kernel(const unsigned int* ei_words, int* flag_int64, long long n_words) {
    __shared__ int nonzero;
    if (threadIdx.x == 0) nonzero = 0;
    __syncthreads();
    long long w = 2LL * threadIdx.x + 1;   // odd word positions = int64 high words
    if (w < n_words) {
        if (ei_words[w] != 0u) atomicOr(&nonzero, 1);
    }
    __syncthreads();
    if (threadIdx.x == 0) *flag_int64 = (nonzero == 0) ? 1 : 0;
}

// ---------- pass 1: per-block bucket histogram over dst (reads raw edge_index) ----------
__global__ __launch_bounds__(BIGT) void bin_count_kernel(
        const void* __restrict__ ei, const int* __restrict__ flag_int64,
        int* __restrict__ blockhist, int E, int NB) {
    __shared__ int h[MAXB];
    int tid = threadIdx.x;
    for (int i = tid; i < NB; i += blockDim.x) h[i] = 0;
    __syncthreads();
    int chunk = (E + gridDim.x - 1) / gridDim.x;
    int s = blockIdx.x * chunk;
    int e = min(E, s + chunk);
    if (*flag_int64) {
        const long long* p = (const long long*)ei;
        for (int i = s + tid; i < e; i += blockDim.x)
            atomicAdd(&h[(int)p[E + i] >> BSHIFT], 1);
    } else {
        const int* p = (const int*)ei;
        for (int i = s + tid; i < e; i += blockDim.x)
            atomicAdd(&h[p[E + i] >> BSHIFT], 1);
    }
    __syncthreads();
    for (int i = tid; i < NB; i += blockDim.x)
        blockhist[i * NBLK + blockIdx.x] = h[i];   // bucket-major for scan
}

// ---------- pass 2: write edges into private (bucket, block) regions; no global atomics ----------
__global__ __launch_bounds__(BIGT) void bin_write_kernel(
        const void* __restrict__ ei, const int* __restrict__ flag_int64,
        const int* __restrict__ offsets, unsigned int* __restrict__ ebuf,
        int E, int NB) {
    __shared__ int cur[MAXB];
    int tid = threadIdx.x;
    for (int i = tid; i < NB; i += blockDim.x)
        cur[i] = offsets[i * NBLK + blockIdx.x];
    __syncthreads();
    int chunk = (E + gridDim.x - 1) / gridDim.x;
    int s = blockIdx.x * chunk;
    int e = min(E, s + chunk);
    if (*flag_int64) {
        const long long* p = (const long long*)ei;
        for (int i = s + tid; i < e; i += blockDim.x) {
            int d = (int)p[E + i];
            int sr = (int)p[i];
            int pos = atomicAdd(&cur[d >> BSHIFT], 1);   // LDS cursor -> private region
            ebuf[pos] = ((unsigned int)(d & (BSZ - 1)) << 20) | (unsigned int)sr;  // src < 2^20
        }
    } else {
        const int* p = (const int*)ei;
        for (int i = s + tid; i < e; i += blockDim.x) {
            int d = p[E + i];
            int sr = p[i];
            int pos = atomicAdd(&cur[d >> BSHIFT], 1);
            ebuf[pos] = ((unsigned int)(d & (BSZ - 1)) << 20) | (unsigned int)sr;
        }
    }
}

// ---------- scan kernel 1: per-1024-chunk local exclusive scan + chunk totals ----------
__global__ void scan_blocks_kernel(const int* __restrict__ cnt, int* __restrict__ ofs,
                                   int* __restrict__ partials, int T) {
    __shared__ int sd[THREADS];
    int tid = threadIdx.x;
    int base = blockIdx.x * 1024 + tid * 4;
    int c0 = (base + 0 < T) ? cnt[base + 0] : 0;
    int c1 = (base + 1 < T) ? cnt[base + 1] : 0;
    int c2 = (base + 2 < T) ? cnt[base + 2] : 0;
    int c3 = (base + 3 < T) ? cnt[base + 3] : 0;
    int tsum = c0 + c1 + c2 + c3;
    sd[tid] = tsum;
    __syncthreads();
    for (int off = 1; off < THREADS; off <<= 1) {
        int t = (tid >= off) ? sd[tid - off] : 0;
        __syncthreads();
        sd[tid] += t;
        __syncthreads();
    }
    int excl = sd[tid] - tsum;
    if (base + 0 < T) ofs[base + 0] = excl;
    if (base + 1 < T) ofs[base + 1] = excl + c0;
    if (base + 2 < T) ofs[base + 2] = excl + c0 + c1;
    if (base + 3 < T) ofs[base + 3] = excl + c0 + c1 + c2;
    if (tid == THREADS - 1) partials[blockIdx.x] = sd[tid];
}

// ---------- scan kernel 2: each block re-scans partials in LDS, adds its prefix ----------
__global__ void scan_add2_kernel(int* __restrict__ ofs, const int* __restrict__ partials,
                                 int T, int SB) {
    __shared__ int sd[128];
    int tid = threadIdx.x;
    if (tid < 128) sd[tid] = (tid < SB) ? partials[tid] : 0;
    __syncthreads();
    for (int off = 1; off < 128; off <<= 1) {
        int t = (tid < 128 && tid >= off) ? sd[tid - off] : 0;
        __syncthreads();
        if (tid < 128) sd[tid] += t;
        __syncthreads();
    }
    int add = (blockIdx.x > 0) ? sd[blockIdx.x - 1] : 0;   // exclusive prefix of this chunk
    int base = blockIdx.x * 1024 + tid * 4;
    if (base + 0 < T) ofs[base + 0] += add;
    if (base + 1 < T) ofs[base + 1] += add;
    if (base + 2 < T) ofs[base + 2] += add;
    if (base + 3 < T) ofs[base + 3] += add;
    if (blockIdx.x == gridDim.x - 1 && tid == 0) ofs[T] = sd[SB - 1];   // grand total = E
}

// ---------- fused per-bucket: degree/rowptr/dinv + col placement + dense1 ----------
// one 1024-thread block per 256-node bucket
__global__ __launch_bounds__(BIGT) void place_dense_kernel(
        const unsigned int* __restrict__ ebuf, const int* __restrict__ offsets,
        const float* __restrict__ x, const float* __restrict__ W1,
        int* __restrict__ rowptr, float* __restrict__ dinv, int* __restrict__ col,
        float* __restrict__ ht1, int N, int NB) {
    __shared__ int cnt[BSZ];
    __shared__ int scanbuf[BSZ];
    __shared__ int baseL[BSZ];
    __shared__ int fillL[BSZ];
    __shared__ float dinvL[BSZ];
    __shared__ float Wt[1024];    // Wt[k*32+j] = W1[j*32+k]
    __shared__ float xs[BIGT];
    int b = blockIdx.x;
    int lo = b << BSHIFT;
    int tid = threadIdx.x;
    if (tid < BSZ) cnt[tid] = 0;
    Wt[(tid & 31) * 32 + (tid >> 5)] = W1[tid];   // BIGT == 1024 covers all
    __syncthreads();
    int start = offsets[b * NBLK];
    int end   = offsets[(b + 1) * NBLK];   // b = NB-1 reads offsets[T] = E
    // pass A: per-node degree count (ebuf region ~32KB, L2-resident)
    for (int p = start + tid; p < end; p += BIGT)
        atomicAdd(&cnt[(ebuf[p] >> 20) & (BSZ - 1)], 1);
    __syncthreads();
    // exclusive scan of cnt (only tid<BSZ touch LDS)
    int c = (tid < BSZ) ? cnt[tid] : 0;
    if (tid < BSZ) scanbuf[tid] = c;
    __syncthreads();
    for (int off = 1; off < BSZ; off <<= 1) {
        int t = (tid < BSZ && tid >= off) ? scanbuf[tid - off] : 0;
        __syncthreads();
        if (tid < BSZ) scanbuf[tid] += t;
        __syncthreads();
    }
    if (tid < BSZ) {
        int excl = scanbuf[tid] - c;
        int node = lo + tid;
        float dv = 1.0f / sqrtf((float)(c + 1));   // +1 self loop
        dinvL[tid] = dv;
        if (node < N) {
            rowptr[node] = start + excl;
            dinv[node] = dv;
            if (node == N - 1) rowptr[N] = start + excl + c;   // == E
        }
        baseL[tid] = start + excl;
        fillL[tid] = 0;
    }
    __syncthreads();
    // pass B: place (col writes confined to this bucket's ~50KB window; ebuf re-read is L2-hit)
    for (int p = start + tid; p < end; p += BIGT) {
        unsigned int v = ebuf[p];
        int dl = (v >> 20) & (BSZ - 1);
        int pos = baseL[dl] + atomicAdd(&fillL[dl], 1);
        col[pos] = (int)(v & 0xFFFFFu);
    }
    __syncthreads();
    // dense1: ht1[n] = (x[n] @ W1^T) * dinv[n]  for this bucket's 256 nodes
    for (int base0 = 0; base0 < BSZ * 32; base0 += BIGT) {
        int idx = base0 + tid;            // 0..8191
        int ln = idx >> 5;                // local node
        int node = lo + ln;
        xs[tid] = (node < N) ? x[(size_t)lo * 32 + idx] : 0.f;
        __syncthreads();
        if (node < N) {
            int j = idx & 31;
            const float* xr = xs + ((tid >> 5) << 5);
            float s = 0.f;
#pragma unroll
            for (int k = 0; k < 32; ++k) s = fmaf(xr[k], Wt[k * 32 + j], s);
            ht1[(size_t)node * 32 + j] = s * dinvL[ln];
        }
        __syncthreads();
    }
}

// ---------- fused agg1 + dense2: ht2 = ((relu(dinv*(gather)+b1)) @ W2^T) * dinv ----------
__global__ __launch_bounds__(THREADS) void agg_dense_kernel(
        const float* __restrict__ ht1, const int* __restrict__ rowptr,
        const int* __restrict__ col, const float* __restrict__ dinv,
        const float* __restrict__ b1, const float* __restrict__ W2,
        float* __restrict__ ht2, int N) {
    __shared__ float Wt[1024];    // Wt[k*32+j] = W2[j*32+k]
    __shared__ float hr[THREADS]; // 8 node-rows of h1
    int tid = threadIdx.x;
    for (int idx = tid; idx < 1024; idx += THREADS)
        Wt[(idx & 31) * 32 + (idx >> 5)] = W2[idx];
    int gid = blockIdx.x * THREADS + tid;
    int n = gid >> 5;
    int j = gid & 31;
    bool act = (n < N);
    float h1v = 0.f, dv = 0.f;
    if (act) {
        dv = dinv[n];
        float s = ht1[gid];               // self loop
        int p = rowptr[n], end = rowptr[n + 1];
        for (; p + 8 <= end; p += 8) {
            int c0 = col[p], c1 = col[p + 1], c2 = col[p + 2], c3 = col[p + 3];
            int c4 = col[p + 4], c5 = col[p + 5], c6 = col[p + 6], c7 = col[p + 7];
            float v0 = ht1[c0 * 32 + j];
            float v1 = ht1[c1 * 32 + j];
            float v2 = ht1[c2 * 32 + j];
            float v3 = ht1[c3 * 32 + j];
            float v4 = ht1[c4 * 32 + j];
            float v5 = ht1[c5 * 32 + j];
            float v6 = ht1[c6 * 32 + j];
            float v7 = ht1[c7 * 32 + j];
            s += ((v0 + v1) + (v2 + v3)) + ((v4 + v5) + (v6 + v7));
        }
        for (; p + 4 <= end; p += 4) {
            int c0 = col[p], c1 = col[p + 1], c2 = col[p + 2], c3 = col[p + 3];
            float v0 = ht1[c0 * 32 + j];
            float v1 = ht1[c1 * 32 + j];
            float v2 = ht1[c2 * 32 + j];
            float v3 = ht1[c3 * 32 + j];
            s += (v0 + v1) + (v2 + v3);
        }
        for (; p < end; ++p) s += ht1[col[p] * 32 + j];
        h1v = fmaxf(fmaf(dv, s, b1[j]), 0.f);
    }
    hr[tid] = h1v;
    __syncthreads();                       // also covers Wt load
    if (act) {
        const float* hrow = hr + ((tid >> 5) << 5);
        float t = 0.f;
#pragma unroll
        for (int k = 0; k < 32; ++k) t = fmaf(hrow[k], Wt[k * 32 + j], t);
        ht2[gid] = t * dv;
    }
}

// ---------- final aggregate: out = relu(dinv * (self + gather) + b2) ----------
__global__ __launch_bounds__(THREADS) void agg_final_kernel(
        const float* __restrict__ ht2, const int* __restrict__ rowptr,
        const int* __restrict__ col, const float* __restrict__ dinv,
        const float* __restrict__ bias, float* __restrict__ out, int N) {
    int gid = blockIdx.x * THREADS + threadIdx.x;
    int n = gid >> 5;
    if (n >= N) return;
    int j = gid & 31;
    float s = ht2[gid];
    int p = rowptr[n], end = rowptr[n + 1];
    for (; p + 8 <= end; p += 8) {
        int c0 = col[p], c1 = col[p + 1], c2 = col[p + 2], c3 = col[p + 3];
        int c4 = col[p + 4], c5 = col[p + 5], c6 = col[p + 6], c7 = col[p + 7];
        float v0 = ht2[c0 * 32 + j];
        float v1 = ht2[c1 * 32 + j];
        float v2 = ht2[c2 * 32 + j];
        float v3 = ht2[c3 * 32 + j];
        float v4 = ht2[c4 * 32 + j];
        float v5 = ht2[c5 * 32 + j];
        float v6 = ht2[c6 * 32 + j];
        float v7 = ht2[c7 * 32 + j];
        s += ((v0 + v1) + (v2 + v3)) + ((v4 + v5) + (v6 + v7));
    }
    for (; p + 4 <= end; p += 4) {
        int c0 = col[p], c1 = col[p + 1], c2 = col[p + 2], c3 = col[p + 3];
        float v0 = ht2[c0 * 32 + j];
        float v1 = ht2[c1 * 32 + j];
        float v2 = ht2[c2 * 32 + j];
        float v3 = ht2[c3 * 32 + j];
        s += (v0 + v1) + (v2 + v3);
    }
    for (; p < end; ++p) s += ht2[col[p] * 32 + j];
    out[gid] = fmaxf(fmaf(dinv[n], s, bias[j]), 0.f);
}

extern "C" void kernel_launch(void* const* d_in, const int* in_sizes, int n_in,
                              void* d_out, int out_size, void* d_ws, size_t ws_size,
                              hipStream_t stream) {
    const float* x  = (const float*)d_in[0];
    const void*  ei = d_in[1];
    const float* W1 = (const float*)d_in[2];
    const float* b1 = (const float*)d_in[3];
    const float* W2 = (const float*)d_in[4];
    const float* b2 = (const float*)d_in[5];
    float* out = (float*)d_out;

    int N = in_sizes[0] / 32;
    long long twoE = (long long)in_sizes[1];
    int E = (int)(twoE / 2);
    int NB = (N + BSZ - 1) >> BSHIFT;          // buckets (391 for N=100000)
    int T  = NB * NBLK;                        // blockhist entries (100096)

    char* ws = (char*)d_ws;
    size_t o = 0;
    auto alloc = [&](size_t bytes) { size_t r = o; o += (bytes + 255) & ~(size_t)255; return r; };
    int*   flag      = (int*)(ws + alloc(4));
    int*   blockhist = (int*)(ws + alloc((size_t)T * 4));
    int*   offsets   = (int*)(ws + alloc((size_t)(T + 1) * 4));
    int*   rowptr    = (int*)(ws + alloc((size_t)(N + 1) * 4));
    int*   partials  = (int*)(ws + alloc(512));
    float* dinv      = (float*)(ws + alloc((size_t)N * 4));
    unsigned int* ebuf = (unsigned int*)(ws + alloc((size_t)E * 4));
    int*   col       = (int*)(ws + alloc((size_t)E * 4));
    float* ht1       = (float*)(ws + alloc((size_t)N * 32 * 4));
    float* ht2       = (float*)(ws + alloc((size_t)N * 32 * 4));

    detect_kernel<<<1, 256, 0, stream>>>((const unsigned int*)ei, flag, twoE);

    bin_count_kernel<<<NBLK, BIGT, 0, stream>>>(ei, flag, blockhist, E, NB);

    int SB = (T + 1023) / 1024;   // 98 (<=128)
    scan_blocks_kernel<<<SB, THREADS, 0, stream>>>(blockhist, offsets, partials, T);
    scan_add2_kernel<<<SB, THREADS, 0, stream>>>(offsets, partials, T, SB);

    bin_write_kernel<<<NBLK, BIGT, 0, stream>>>(ei, flag, offsets, ebuf, E, NB);
    place_dense_kernel<<<NB, BIGT, 0, stream>>>(ebuf, offsets, x, W1, rowptr, dinv, col, ht1, N, NB);

    int GB = (N * 32 + THREADS - 1) / THREADS;
    agg_dense_kernel<<<GB, THREADS, 0, stream>>>(ht1, rowptr, col, dinv, b1, W2, ht2, N);
    agg_final_kernel<<<GB, THREADS, 0, stream>>>(ht2, rowptr, col, dinv, b2, out, N);
}